// Round 1
// baseline (234.973 us; speedup 1.0000x reference)
//
#include <hip/hip_runtime.h>
#include <hip/hip_bf16.h>
#include <math.h>

#define Bsz 4
#define Slen 2048
#define Hdim 576
#define NH 9
#define NKV 3
#define HD 64
#define MAXPOS 8192

typedef __bf16 bf16_t;
typedef __bf16 bf16x8 __attribute__((ext_vector_type(8)));
typedef float f32x4 __attribute__((ext_vector_type(4)));

static __device__ __forceinline__ bf16x8 load_cvt8(const float* __restrict__ src){
  float4 f0 = *reinterpret_cast<const float4*>(src);
  float4 f1 = *reinterpret_cast<const float4*>(src + 4);
  bf16x8 v;
  v[0]=(bf16_t)f0.x; v[1]=(bf16_t)f0.y; v[2]=(bf16_t)f0.z; v[3]=(bf16_t)f0.w;
  v[4]=(bf16_t)f1.x; v[5]=(bf16_t)f1.y; v[6]=(bf16_t)f1.z; v[7]=(bf16_t)f1.w;
  return v;
}

// ---------------- RoPE tables: cos/sin[pos][j], j = 0..31 ----------------
__global__ void rope_table_kernel(float* __restrict__ cost, float* __restrict__ sint){
  int i = blockIdx.x * blockDim.x + threadIdx.x;
  if (i >= MAXPOS * 32) return;
  int j = i & 31;
  int p = i >> 5;
  double invf = pow(100000.0, -(double)j / 32.0);
  double ang = (double)p * invf;
  cost[i] = (float)cos(ang);
  sint[i] = (float)sin(ang);
}

// ---------------- QKV projection GEMM (M=8192, K=576, N=960) ----------------
// BM=128, BN=64 (one head per n-tile), BK=64. 4 waves (2x2), wave tile 64x32.
// Writes q,k as (b,h,s,d) bf16; v transposed as (b,kvh,d,s) bf16.
__launch_bounds__(256)
__global__ void qkv_gemm_kernel(const float* __restrict__ X,
                                const float* __restrict__ Wq,
                                const float* __restrict__ Wk,
                                const float* __restrict__ Wv,
                                bf16_t* __restrict__ qbuf,
                                bf16_t* __restrict__ kbuf,
                                bf16_t* __restrict__ vtbuf)
{
  __shared__ bf16_t Ald[128 * 72];  // pad to 72 bf16 (144B = 9 x 16B slots) -> conflict-free b128
  __shared__ bf16_t Bld[64 * 72];
  const int t = threadIdx.x;
  const int l = t & 63;
  const int wid = t >> 6;
  const int wm = wid >> 1, wn = wid & 1;
  const int lane16 = l & 15, grp = l >> 4;
  const int m0 = blockIdx.x * 128;
  const int nt = blockIdx.y;   // 0..14; 0-8 -> Q head nt, 9-11 -> K head nt-9, 12-14 -> V head nt-12

  const float* Wsrc;
  int nrow0;
  if (nt < 9)      { Wsrc = Wq; nrow0 = nt * 64; }
  else if (nt < 12){ Wsrc = Wk; nrow0 = (nt - 9) * 64; }
  else             { Wsrc = Wv; nrow0 = (nt - 12) * 64; }

  const f32x4 fzero = {0.f, 0.f, 0.f, 0.f};
  f32x4 acc[4][2];
  #pragma unroll
  for (int mi = 0; mi < 4; ++mi)
    #pragma unroll
    for (int ni = 0; ni < 2; ++ni)
      acc[mi][ni] = fzero;

  const int rA = t >> 1, kA = (t & 1) * 32;   // A: 128 rows x 64 k, 32 fp32 per thread
  const int rB = t >> 2, kB = (t & 3) * 16;   // B: 64 rows x 64 k, 16 fp32 per thread

  for (int kt = 0; kt < 9; ++kt){
    {
      const float* asrc = X + (size_t)(m0 + rA) * Hdim + kt * 64 + kA;
      bf16_t* adst = Ald + rA * 72 + kA;
      #pragma unroll
      for (int u = 0; u < 4; ++u)
        *reinterpret_cast<bf16x8*>(adst + u * 8) = load_cvt8(asrc + u * 8);
      const float* bsrc = Wsrc + (size_t)(nrow0 + rB) * Hdim + kt * 64 + kB;
      bf16_t* bdst = Bld + rB * 72 + kB;
      #pragma unroll
      for (int u = 0; u < 2; ++u)
        *reinterpret_cast<bf16x8*>(bdst + u * 8) = load_cvt8(bsrc + u * 8);
    }
    __syncthreads();
    #pragma unroll
    for (int ks = 0; ks < 2; ++ks){
      bf16x8 a[4], bb[2];
      #pragma unroll
      for (int mi = 0; mi < 4; ++mi)
        a[mi] = *reinterpret_cast<const bf16x8*>(&Ald[(wm * 64 + mi * 16 + lane16) * 72 + ks * 32 + grp * 8]);
      #pragma unroll
      for (int ni = 0; ni < 2; ++ni)
        bb[ni] = *reinterpret_cast<const bf16x8*>(&Bld[(wn * 32 + ni * 16 + lane16) * 72 + ks * 32 + grp * 8]);
      #pragma unroll
      for (int mi = 0; mi < 4; ++mi)
        #pragma unroll
        for (int ni = 0; ni < 2; ++ni)
          acc[mi][ni] = __builtin_amdgcn_mfma_f32_16x16x32_bf16(a[mi], bb[ni], acc[mi][ni], 0, 0, 0);
    }
    __syncthreads();
  }

  // Epilogue: C/D layout col=lane&15, row=(lane>>4)*4+j (verified m89)
  #pragma unroll
  for (int mi = 0; mi < 4; ++mi){
    #pragma unroll
    for (int ni = 0; ni < 2; ++ni){
      #pragma unroll
      for (int j = 0; j < 4; ++j){
        int m = m0 + wm * 64 + mi * 16 + grp * 4 + j;
        int dl = wn * 32 + ni * 16 + lane16;      // 0..63 = head-dim
        int b = m >> 11;
        int s = m & 2047;
        bf16_t v = (bf16_t)acc[mi][ni][j];
        if (nt < 9)
          qbuf[(((size_t)b * NH + nt) * Slen + s) * HD + dl] = v;
        else if (nt < 12)
          kbuf[(((size_t)b * NKV + (nt - 9)) * Slen + s) * HD + dl] = v;
        else
          vtbuf[(((size_t)b * NKV + (nt - 12)) * HD + dl) * Slen + s] = v;
      }
    }
  }
}

// ---------------- RoPE in-place on (b,h,s,d) bf16 rows ----------------
__global__ void rope_apply_kernel(bf16_t* __restrict__ buf, const int* __restrict__ pos_ids,
                                  const float* __restrict__ cost, const float* __restrict__ sint,
                                  int nheads)
{
  int idx = blockIdx.x * blockDim.x + threadIdx.x;  // one thread per (b,h,s) row
  int total = Bsz * nheads * Slen;
  if (idx >= total) return;
  int s = idx % Slen;
  int b = idx / (nheads * Slen);
  bf16_t* row = buf + (size_t)idx * HD;
  int pos = pos_ids[b * Slen + s];
  const float* cp = cost + (size_t)pos * 32;
  const float* sp = sint + (size_t)pos * 32;
  float x[64];
  #pragma unroll
  for (int v = 0; v < 8; ++v){
    bf16x8 t8 = *reinterpret_cast<const bf16x8*>(row + v * 8);
    #pragma unroll
    for (int i = 0; i < 8; ++i) x[v * 8 + i] = (float)t8[i];
  }
  bf16_t o[64];
  #pragma unroll
  for (int j = 0; j < 32; ++j){
    float c = cp[j], sn = sp[j];
    o[j]      = (bf16_t)(x[j] * c - x[j + 32] * sn);
    o[j + 32] = (bf16_t)(x[j + 32] * c + x[j] * sn);
  }
  #pragma unroll
  for (int v = 0; v < 8; ++v)
    *reinterpret_cast<bf16x8*>(row + v * 8) = *reinterpret_cast<bf16x8*>(o + v * 8);
}

// ---------------- Flash attention, causal, GQA ----------------
// Block = (qt, b*NH + h): 64 q-rows, 4 waves x 16 rows. KV tiles of 64.
__launch_bounds__(256)
__global__ void flash_attn_kernel(const bf16_t* __restrict__ qbuf,
                                  const bf16_t* __restrict__ kbuf,
                                  const bf16_t* __restrict__ vtbuf,
                                  bf16_t* __restrict__ attn_out)
{
  __shared__ bf16_t Kld[64 * 72];       // [s_k][d]
  __shared__ bf16_t Vld[64 * 72];       // [d][s_k]  (V stored transposed)
  __shared__ bf16_t Pld[4 * 16 * 72];   // per-wave P tile [16 q][64 k]
  const int t = threadIdx.x, l = t & 63, w = t >> 6;
  const int lane16 = l & 15, grp = l >> 4;
  const int qt = blockIdx.x;            // 0..31
  const int bh = blockIdx.y;            // 0..35
  const int b = bh / NH, h = bh % NH, kvh = h / (NH / NKV);

  const bf16_t* qp = qbuf + ((size_t)b * NH + h) * Slen * HD;
  const bf16_t* kp = kbuf + ((size_t)b * NKV + kvh) * Slen * HD;
  const bf16_t* vp = vtbuf + ((size_t)b * NKV + kvh) * HD * Slen;

  const int q0 = qt * 64 + w * 16;
  // Q fragments live in registers for the whole KV loop
  bf16x8 aq[2];
  #pragma unroll
  for (int ks = 0; ks < 2; ++ks)
    aq[ks] = *reinterpret_cast<const bf16x8*>(qp + (size_t)(q0 + lane16) * HD + ks * 32 + grp * 8);

  const f32x4 fzero = {0.f, 0.f, 0.f, 0.f};
  f32x4 acco[4];
  #pragma unroll
  for (int di = 0; di < 4; ++di) acco[di] = fzero;
  float mrun[4], lrun[4];
  #pragma unroll
  for (int j = 0; j < 4; ++j){ mrun[j] = -1e30f; lrun[j] = 0.f; }

  const int rS = t >> 2, cS = (t & 3) * 16;  // staging: 4 threads per row
  const int ntiles = qt + 1;                 // causal skip
  for (int kb = 0; kb < ntiles; ++kb){
    const int k0 = kb * 64;
    {
      const bf16_t* ksrc = kp + (size_t)(k0 + rS) * HD + cS;
      *reinterpret_cast<bf16x8*>(&Kld[rS * 72 + cS])     = *reinterpret_cast<const bf16x8*>(ksrc);
      *reinterpret_cast<bf16x8*>(&Kld[rS * 72 + cS + 8]) = *reinterpret_cast<const bf16x8*>(ksrc + 8);
      const bf16_t* vsrc = vp + (size_t)rS * Slen + k0 + cS;
      *reinterpret_cast<bf16x8*>(&Vld[rS * 72 + cS])     = *reinterpret_cast<const bf16x8*>(vsrc);
      *reinterpret_cast<bf16x8*>(&Vld[rS * 72 + cS + 8]) = *reinterpret_cast<const bf16x8*>(vsrc + 8);
    }
    __syncthreads();

    // scores = Q K^T : n-dim = key position
    f32x4 sacc[4];
    #pragma unroll
    for (int ni = 0; ni < 4; ++ni) sacc[ni] = fzero;
    #pragma unroll
    for (int ks = 0; ks < 2; ++ks){
      #pragma unroll
      for (int ni = 0; ni < 4; ++ni){
        bf16x8 bk = *reinterpret_cast<const bf16x8*>(&Kld[(ni * 16 + lane16) * 72 + ks * 32 + grp * 8]);
        sacc[ni] = __builtin_amdgcn_mfma_f32_16x16x32_bf16(aq[ks], bk, sacc[ni], 0, 0, 0);
      }
    }

    // scale + causal mask (diagonal tile only) + row max
    const bool diag = (kb == qt);
    float tmax[4] = {-1e30f, -1e30f, -1e30f, -1e30f};
    #pragma unroll
    for (int ni = 0; ni < 4; ++ni){
      int kcol = ni * 16 + lane16;  // within tile
      #pragma unroll
      for (int j = 0; j < 4; ++j){
        float v = sacc[ni][j] * 0.125f;
        if (diag && (kcol > w * 16 + grp * 4 + j)) v = -1e30f;
        sacc[ni][j] = v;
        tmax[j] = fmaxf(tmax[j], v);
      }
    }
    #pragma unroll
    for (int off = 1; off < 16; off <<= 1){
      #pragma unroll
      for (int j = 0; j < 4; ++j)
        tmax[j] = fmaxf(tmax[j], __shfl_xor(tmax[j], off, 64));
    }
    float mnew[4], sf[4], rsum[4];
    #pragma unroll
    for (int j = 0; j < 4; ++j){
      mnew[j] = fmaxf(mrun[j], tmax[j]);
      sf[j] = __expf(mrun[j] - mnew[j]);
      rsum[j] = 0.f;
    }
    #pragma unroll
    for (int ni = 0; ni < 4; ++ni){
      #pragma unroll
      for (int j = 0; j < 4; ++j){
        float p = __expf(sacc[ni][j] - mnew[j]);
        sacc[ni][j] = p;
        rsum[j] += p;
      }
    }
    #pragma unroll
    for (int off = 1; off < 16; off <<= 1){
      #pragma unroll
      for (int j = 0; j < 4; ++j)
        rsum[j] += __shfl_xor(rsum[j], off, 64);
    }
    #pragma unroll
    for (int j = 0; j < 4; ++j){
      lrun[j] = lrun[j] * sf[j] + rsum[j];
      mrun[j] = mnew[j];
    }
    #pragma unroll
    for (int di = 0; di < 4; ++di)
      #pragma unroll
      for (int j = 0; j < 4; ++j)
        acco[di][j] *= sf[j];

    // P (scores layout, col=k) -> LDS -> A-fragment layout (row=q, k contiguous)
    #pragma unroll
    for (int ni = 0; ni < 4; ++ni)
      #pragma unroll
      for (int j = 0; j < 4; ++j)
        Pld[w * 16 * 72 + (grp * 4 + j) * 72 + ni * 16 + lane16] = (bf16_t)sacc[ni][j];

    // PV: A = P[16 q][64 k], B = Vt[d][s_k]
    #pragma unroll
    for (int ks = 0; ks < 2; ++ks){
      bf16x8 pa = *reinterpret_cast<const bf16x8*>(&Pld[w * 16 * 72 + lane16 * 72 + ks * 32 + grp * 8]);
      #pragma unroll
      for (int di = 0; di < 4; ++di){
        bf16x8 bv = *reinterpret_cast<const bf16x8*>(&Vld[(di * 16 + lane16) * 72 + ks * 32 + grp * 8]);
        acco[di] = __builtin_amdgcn_mfma_f32_16x16x32_bf16(pa, bv, acco[di], 0, 0, 0);
      }
    }
    __syncthreads();
  }

  // write attn out (b, s, h*64+d) bf16
  #pragma unroll
  for (int di = 0; di < 4; ++di){
    #pragma unroll
    for (int j = 0; j < 4; ++j){
      int s = q0 + grp * 4 + j;
      float v = acco[di][j] / lrun[j];
      attn_out[((size_t)b * Slen + s) * (NH * HD) + h * HD + di * 16 + lane16] = (bf16_t)v;
    }
  }
}

// ---------------- Output GEMM: attn (8192x576 bf16) @ Wo^T (576x576) -> fp32 ----------------
__launch_bounds__(256)
__global__ void out_gemm_kernel(const bf16_t* __restrict__ A,
                                const float* __restrict__ Wo,
                                float* __restrict__ out)
{
  __shared__ bf16_t Ald[128 * 72];
  __shared__ bf16_t Bld[64 * 72];
  const int t = threadIdx.x;
  const int l = t & 63;
  const int wid = t >> 6;
  const int wm = wid >> 1, wn = wid & 1;
  const int lane16 = l & 15, grp = l >> 4;
  const int m0 = blockIdx.x * 128;
  const int nt = blockIdx.y;   // 0..8

  const f32x4 fzero = {0.f, 0.f, 0.f, 0.f};
  f32x4 acc[4][2];
  #pragma unroll
  for (int mi = 0; mi < 4; ++mi)
    #pragma unroll
    for (int ni = 0; ni < 2; ++ni)
      acc[mi][ni] = fzero;

  const int rA = t >> 1, kA = (t & 1) * 32;
  const int rB = t >> 2, kB = (t & 3) * 16;

  for (int kt = 0; kt < 9; ++kt){
    {
      const bf16_t* asrc = A + (size_t)(m0 + rA) * Hdim + kt * 64 + kA;
      bf16_t* adst = Ald + rA * 72 + kA;
      #pragma unroll
      for (int u = 0; u < 4; ++u)
        *reinterpret_cast<bf16x8*>(adst + u * 8) = *reinterpret_cast<const bf16x8*>(asrc + u * 8);
      const float* bsrc = Wo + (size_t)(nt * 64 + rB) * Hdim + kt * 64 + kB;
      bf16_t* bdst = Bld + rB * 72 + kB;
      #pragma unroll
      for (int u = 0; u < 2; ++u)
        *reinterpret_cast<bf16x8*>(bdst + u * 8) = load_cvt8(bsrc + u * 8);
    }
    __syncthreads();
    #pragma unroll
    for (int ks = 0; ks < 2; ++ks){
      bf16x8 a[4], bb[2];
      #pragma unroll
      for (int mi = 0; mi < 4; ++mi)
        a[mi] = *reinterpret_cast<const bf16x8*>(&Ald[(wm * 64 + mi * 16 + lane16) * 72 + ks * 32 + grp * 8]);
      #pragma unroll
      for (int ni = 0; ni < 2; ++ni)
        bb[ni] = *reinterpret_cast<const bf16x8*>(&Bld[(wn * 32 + ni * 16 + lane16) * 72 + ks * 32 + grp * 8]);
      #pragma unroll
      for (int mi = 0; mi < 4; ++mi)
        #pragma unroll
        for (int ni = 0; ni < 2; ++ni)
          acc[mi][ni] = __builtin_amdgcn_mfma_f32_16x16x32_bf16(a[mi], bb[ni], acc[mi][ni], 0, 0, 0);
    }
    __syncthreads();
  }

  #pragma unroll
  for (int mi = 0; mi < 4; ++mi){
    #pragma unroll
    for (int ni = 0; ni < 2; ++ni){
      #pragma unroll
      for (int j = 0; j < 4; ++j){
        int m = m0 + wm * 64 + mi * 16 + grp * 4 + j;
        int n = nt * 64 + wn * 32 + ni * 16 + lane16;
        out[(size_t)m * Hdim + n] = acc[mi][ni][j];
      }
    }
  }
}

extern "C" void kernel_launch(void* const* d_in, const int* in_sizes, int n_in,
                              void* d_out, int out_size, void* d_ws, size_t ws_size,
                              hipStream_t stream) {
  const float* X   = (const float*)d_in[0];
  // d_in[1] = attention_mask: deterministic causal -> not read
  const int* pos   = (const int*)d_in[2];
  const float* Wq  = (const float*)d_in[3];
  const float* Wk  = (const float*)d_in[4];
  const float* Wv  = (const float*)d_in[5];
  const float* Wo  = (const float*)d_in[6];
  float* out = (float*)d_out;

  char* ws = (char*)d_ws;
  float* cost = (float*)ws;                                     // 1 MB
  float* sint = (float*)(ws + (size_t)MAXPOS * 32 * 4);         // 1 MB
  bf16_t* qb = (bf16_t*)(ws + 2 * (size_t)MAXPOS * 32 * 4);     // 9.44 MB
  bf16_t* kb = qb + (size_t)Bsz * NH * Slen * HD;               // 3.15 MB
  bf16_t* vt = kb + (size_t)Bsz * NKV * Slen * HD;              // 3.15 MB
  bf16_t* ab = vt + (size_t)Bsz * NKV * Slen * HD;              // 9.44 MB

  rope_table_kernel<<<dim3((MAXPOS * 32 + 255) / 256), dim3(256), 0, stream>>>(cost, sint);
  qkv_gemm_kernel<<<dim3(64, 15), dim3(256), 0, stream>>>(X, Wq, Wk, Wv, qb, kb, vt);
  rope_apply_kernel<<<dim3((Bsz * NH * Slen + 255) / 256), dim3(256), 0, stream>>>(qb, pos, cost, sint, NH);
  rope_apply_kernel<<<dim3((Bsz * NKV * Slen + 255) / 256), dim3(256), 0, stream>>>(kb, pos, cost, sint, NKV);
  flash_attn_kernel<<<dim3(32, 36), dim3(256), 0, stream>>>(qb, kb, vt, ab);
  out_gemm_kernel<<<dim3(64, 9), dim3(256), 0, stream>>>(ab, Wo, out);
}

// Round 2
// 181.473 us; speedup vs baseline: 1.2948x; 1.2948x over previous
//
#include <hip/hip_runtime.h>
#include <hip/hip_bf16.h>
#include <math.h>

#define Bsz 4
#define Slen 2048
#define Hdim 576
#define NH 9
#define NKV 3
#define HD 64
#define MAXPOS 8192

typedef __bf16 bf16_t;
typedef __bf16 bf16x8 __attribute__((ext_vector_type(8)));
typedef float f32x4 __attribute__((ext_vector_type(4)));

static __device__ __forceinline__ bf16x8 load_cvt8(const float* __restrict__ src){
  float4 f0 = *reinterpret_cast<const float4*>(src);
  float4 f1 = *reinterpret_cast<const float4*>(src + 4);
  bf16x8 v;
  v[0]=(bf16_t)f0.x; v[1]=(bf16_t)f0.y; v[2]=(bf16_t)f0.z; v[3]=(bf16_t)f0.w;
  v[4]=(bf16_t)f1.x; v[5]=(bf16_t)f1.y; v[6]=(bf16_t)f1.z; v[7]=(bf16_t)f1.w;
  return v;
}

// async global->LDS, 16B per lane; LDS dest = wave-uniform base + lane*16
static __device__ __forceinline__ void gload16(const bf16_t* g, bf16_t* l){
  __builtin_amdgcn_global_load_lds((const __attribute__((address_space(1))) void*)g,
                                   (__attribute__((address_space(3))) void*)l, 16, 0, 0);
}

// ---------------- RoPE tables: cos/sin[pos][j], j = 0..31 ----------------
__global__ void rope_table_kernel(float* __restrict__ cost, float* __restrict__ sint){
  int i = blockIdx.x * blockDim.x + threadIdx.x;
  if (i >= MAXPOS * 32) return;
  int j = i & 31;
  int p = i >> 5;
  double invf = pow(100000.0, -(double)j / 32.0);
  double ang = (double)p * invf;
  cost[i] = (float)cos(ang);
  sint[i] = (float)sin(ang);
}

// ---------------- QKV projection GEMM (M=8192, K=576, N=960) ----------------
__launch_bounds__(256)
__global__ void qkv_gemm_kernel(const float* __restrict__ X,
                                const float* __restrict__ Wq,
                                const float* __restrict__ Wk,
                                const float* __restrict__ Wv,
                                bf16_t* __restrict__ qbuf,
                                bf16_t* __restrict__ kbuf,
                                bf16_t* __restrict__ vtbuf)
{
  __shared__ bf16_t Ald[128 * 72];
  __shared__ bf16_t Bld[64 * 72];
  const int t = threadIdx.x;
  const int l = t & 63;
  const int wid = t >> 6;
  const int wm = wid >> 1, wn = wid & 1;
  const int lane16 = l & 15, grp = l >> 4;
  const int m0 = blockIdx.x * 128;
  const int nt = blockIdx.y;

  const float* Wsrc;
  int nrow0;
  if (nt < 9)      { Wsrc = Wq; nrow0 = nt * 64; }
  else if (nt < 12){ Wsrc = Wk; nrow0 = (nt - 9) * 64; }
  else             { Wsrc = Wv; nrow0 = (nt - 12) * 64; }

  const f32x4 fzero = {0.f, 0.f, 0.f, 0.f};
  f32x4 acc[4][2];
  #pragma unroll
  for (int mi = 0; mi < 4; ++mi)
    #pragma unroll
    for (int ni = 0; ni < 2; ++ni)
      acc[mi][ni] = fzero;

  const int rA = t >> 1, kA = (t & 1) * 32;
  const int rB = t >> 2, kB = (t & 3) * 16;

  for (int kt = 0; kt < 9; ++kt){
    {
      const float* asrc = X + (size_t)(m0 + rA) * Hdim + kt * 64 + kA;
      bf16_t* adst = Ald + rA * 72 + kA;
      #pragma unroll
      for (int u = 0; u < 4; ++u)
        *reinterpret_cast<bf16x8*>(adst + u * 8) = load_cvt8(asrc + u * 8);
      const float* bsrc = Wsrc + (size_t)(nrow0 + rB) * Hdim + kt * 64 + kB;
      bf16_t* bdst = Bld + rB * 72 + kB;
      #pragma unroll
      for (int u = 0; u < 2; ++u)
        *reinterpret_cast<bf16x8*>(bdst + u * 8) = load_cvt8(bsrc + u * 8);
    }
    __syncthreads();
    #pragma unroll
    for (int ks = 0; ks < 2; ++ks){
      bf16x8 a[4], bb[2];
      #pragma unroll
      for (int mi = 0; mi < 4; ++mi)
        a[mi] = *reinterpret_cast<const bf16x8*>(&Ald[(wm * 64 + mi * 16 + lane16) * 72 + ks * 32 + grp * 8]);
      #pragma unroll
      for (int ni = 0; ni < 2; ++ni)
        bb[ni] = *reinterpret_cast<const bf16x8*>(&Bld[(wn * 32 + ni * 16 + lane16) * 72 + ks * 32 + grp * 8]);
      #pragma unroll
      for (int mi = 0; mi < 4; ++mi)
        #pragma unroll
        for (int ni = 0; ni < 2; ++ni)
          acc[mi][ni] = __builtin_amdgcn_mfma_f32_16x16x32_bf16(a[mi], bb[ni], acc[mi][ni], 0, 0, 0);
    }
    __syncthreads();
  }

  #pragma unroll
  for (int mi = 0; mi < 4; ++mi){
    #pragma unroll
    for (int ni = 0; ni < 2; ++ni){
      #pragma unroll
      for (int j = 0; j < 4; ++j){
        int m = m0 + wm * 64 + mi * 16 + grp * 4 + j;
        int dl = wn * 32 + ni * 16 + lane16;
        int b = m >> 11;
        int s = m & 2047;
        bf16_t v = (bf16_t)acc[mi][ni][j];
        if (nt < 9)
          qbuf[(((size_t)b * NH + nt) * Slen + s) * HD + dl] = v;
        else if (nt < 12)
          kbuf[(((size_t)b * NKV + (nt - 9)) * Slen + s) * HD + dl] = v;
        else
          vtbuf[(((size_t)b * NKV + (nt - 12)) * HD + dl) * Slen + s] = v;
      }
    }
  }
}

// ---------------- RoPE in-place, with output scale (folds attn scale into Q) ----------------
__global__ void rope_apply_kernel(bf16_t* __restrict__ buf, const int* __restrict__ pos_ids,
                                  const float* __restrict__ cost, const float* __restrict__ sint,
                                  int nheads, float scale)
{
  int idx = blockIdx.x * blockDim.x + threadIdx.x;
  int total = Bsz * nheads * Slen;
  if (idx >= total) return;
  int s = idx % Slen;
  int b = idx / (nheads * Slen);
  bf16_t* row = buf + (size_t)idx * HD;
  int pos = pos_ids[b * Slen + s];
  const float* cp = cost + (size_t)pos * 32;
  const float* sp = sint + (size_t)pos * 32;
  float x[64];
  #pragma unroll
  for (int v = 0; v < 8; ++v){
    bf16x8 t8 = *reinterpret_cast<const bf16x8*>(row + v * 8);
    #pragma unroll
    for (int i = 0; i < 8; ++i) x[v * 8 + i] = (float)t8[i];
  }
  bf16_t o[64];
  #pragma unroll
  for (int j = 0; j < 32; ++j){
    float c = cp[j], sn = sp[j];
    o[j]      = (bf16_t)((x[j] * c - x[j + 32] * sn) * scale);
    o[j + 32] = (bf16_t)((x[j + 32] * c + x[j] * sn) * scale);
  }
  #pragma unroll
  for (int v = 0; v < 8; ++v)
    *reinterpret_cast<bf16x8*>(row + v * 8) = *reinterpret_cast<bf16x8*>(o + v * 8);
}

// ---------------- Flash attention v2: gload_lds + swizzle, dbuf 2-phase, balanced schedule ----------------
// Block = 64 q-rows, 4 waves x 16 rows. KV tiles of 64, double-buffered.
// K/V LDS: linear [64 rows][64 elems]; content [r][c16] = global [r][c16 ^ (r&7)] (16B chunks).
__launch_bounds__(256)
__global__ void flash_attn_kernel(const bf16_t* __restrict__ qbuf,
                                  const bf16_t* __restrict__ kbuf,
                                  const bf16_t* __restrict__ vtbuf,
                                  bf16_t* __restrict__ attn_out)
{
  __shared__ bf16_t Kld[2][64 * 64];
  __shared__ bf16_t Vld[2][64 * 64];
  __shared__ bf16_t Pld[4][16 * 72];
  const int t = threadIdx.x, l = t & 63, w = t >> 6;
  const int lane16 = l & 15, grp = l >> 4;

  // balanced + XCD-chunked schedule: 1152 blocks = 8 XCD chunks of 144
  const int flat = blockIdx.y * 32 + blockIdx.x;
  const int nf = (flat & 7) * 144 + (flat >> 3);
  const int bh = nf >> 5;
  const int qt = 31 - (nf & 31);          // big blocks first within each chunk
  const int b = bh / NH, h = bh % NH, kvh = h / (NH / NKV);

  const bf16_t* qp = qbuf + ((size_t)b * NH + h) * Slen * HD;
  const bf16_t* kp = kbuf + ((size_t)b * NKV + kvh) * Slen * HD;
  const bf16_t* vp = vtbuf + ((size_t)b * NKV + kvh) * HD * Slen;

  const int q0 = qt * 64 + w * 16;
  bf16x8 aq[2];
  #pragma unroll
  for (int ks = 0; ks < 2; ++ks)
    aq[ks] = *reinterpret_cast<const bf16x8*>(qp + (size_t)(q0 + lane16) * HD + ks * 32 + grp * 8);

  const f32x4 fzero = {0.f, 0.f, 0.f, 0.f};
  f32x4 acco[4];
  #pragma unroll
  for (int di = 0; di < 4; ++di) acco[di] = fzero;
  float mrun[4], lrun[4];
  #pragma unroll
  for (int j = 0; j < 4; ++j){ mrun[j] = -1e30f; lrun[j] = 0.f; }

  // staging geometry: per wave 2 issues of 1KB each for K and for V
  const int sr = l >> 3;                   // 0..7 sub-row within 8-row chunk
  const int sc = ((l & 7) ^ sr) * 8;       // swizzled source col (elems)

  const int ntiles = qt + 1;
  int cur = 0;

  // prologue: stage tile 0 into buf 0
  {
    const int k0_ = 0;
    #pragma unroll
    for (int u = 0; u < 2; ++u){
      int r = (w * 2 + u) * 8 + sr;
      gload16(kp + (size_t)(k0_ + r) * HD + sc, &Kld[0][(w * 2 + u) * 512]);
      gload16(vp + (size_t)r * Slen + k0_ + sc, &Vld[0][(w * 2 + u) * 512]);
    }
  }
  asm volatile("s_waitcnt vmcnt(0)" ::: "memory");
  __syncthreads();

  for (int kb = 0; kb < ntiles; ++kb){
    // issue next-tile stage into the other buffer (overlaps with compute below)
    if (kb + 1 < ntiles){
      const int k0_ = (kb + 1) * 64;
      #pragma unroll
      for (int u = 0; u < 2; ++u){
        int r = (w * 2 + u) * 8 + sr;
        gload16(kp + (size_t)(k0_ + r) * HD + sc, &Kld[cur ^ 1][(w * 2 + u) * 512]);
        gload16(vp + (size_t)r * Slen + k0_ + sc, &Vld[cur ^ 1][(w * 2 + u) * 512]);
      }
    }

    // ---- QK^T on buf cur (swizzled reads) ----
    f32x4 sacc[4];
    #pragma unroll
    for (int ni = 0; ni < 4; ++ni) sacc[ni] = fzero;
    #pragma unroll
    for (int ks = 0; ks < 2; ++ks){
      #pragma unroll
      for (int ni = 0; ni < 4; ++ni){
        int row = ni * 16 + lane16;
        bf16x8 bk = *reinterpret_cast<const bf16x8*>(
            &Kld[cur][row * 64 + (((ks * 4 + grp) ^ (row & 7)) * 8)]);
        sacc[ni] = __builtin_amdgcn_mfma_f32_16x16x32_bf16(aq[ks], bk, sacc[ni], 0, 0, 0);
      }
    }

    // ---- softmax (log2 domain; Q pre-scaled by 0.125*log2e) ----
    const bool diag = (kb == qt);
    float tmax[4] = {-1e30f, -1e30f, -1e30f, -1e30f};
    #pragma unroll
    for (int ni = 0; ni < 4; ++ni){
      int kcol = ni * 16 + lane16;
      #pragma unroll
      for (int j = 0; j < 4; ++j){
        float v = sacc[ni][j];
        if (diag && (kcol > w * 16 + grp * 4 + j)) v = -1e30f;
        sacc[ni][j] = v;
        tmax[j] = fmaxf(tmax[j], v);
      }
    }
    #pragma unroll
    for (int off = 1; off < 16; off <<= 1){
      #pragma unroll
      for (int j = 0; j < 4; ++j)
        tmax[j] = fmaxf(tmax[j], __shfl_xor(tmax[j], off, 64));
    }
    float mnew[4], sf[4], rsum[4];
    #pragma unroll
    for (int j = 0; j < 4; ++j){
      mnew[j] = fmaxf(mrun[j], tmax[j]);
      sf[j] = __builtin_amdgcn_exp2f(mrun[j] - mnew[j]);
      rsum[j] = 0.f;
    }
    #pragma unroll
    for (int ni = 0; ni < 4; ++ni){
      #pragma unroll
      for (int j = 0; j < 4; ++j){
        float p = __builtin_amdgcn_exp2f(sacc[ni][j] - mnew[j]);
        sacc[ni][j] = p;
        rsum[j] += p;
      }
    }
    #pragma unroll
    for (int off = 1; off < 16; off <<= 1){
      #pragma unroll
      for (int j = 0; j < 4; ++j)
        rsum[j] += __shfl_xor(rsum[j], off, 64);
    }
    #pragma unroll
    for (int j = 0; j < 4; ++j){
      lrun[j] = lrun[j] * sf[j] + rsum[j];
      mrun[j] = mnew[j];
    }
    #pragma unroll
    for (int di = 0; di < 4; ++di)
      #pragma unroll
      for (int j = 0; j < 4; ++j)
        acco[di][j] *= sf[j];

    // ---- P -> per-wave LDS (no barrier needed) -> A-fragment ----
    #pragma unroll
    for (int ni = 0; ni < 4; ++ni)
      #pragma unroll
      for (int j = 0; j < 4; ++j)
        Pld[w][(grp * 4 + j) * 72 + ni * 16 + lane16] = (bf16_t)sacc[ni][j];

    // ---- PV on buf cur (swizzled V reads) ----
    #pragma unroll
    for (int ks = 0; ks < 2; ++ks){
      bf16x8 pa = *reinterpret_cast<const bf16x8*>(&Pld[w][lane16 * 72 + ks * 32 + grp * 8]);
      #pragma unroll
      for (int di = 0; di < 4; ++di){
        int row = di * 16 + lane16;
        bf16x8 bv = *reinterpret_cast<const bf16x8*>(
            &Vld[cur][row * 64 + (((ks * 4 + grp) ^ (row & 7)) * 8)]);
        acco[di] = __builtin_amdgcn_mfma_f32_16x16x32_bf16(pa, bv, acco[di], 0, 0, 0);
      }
    }

    // next-tile staged AND everyone done reading buf cur
    asm volatile("s_waitcnt vmcnt(0)" ::: "memory");
    __syncthreads();
    cur ^= 1;
  }

  #pragma unroll
  for (int di = 0; di < 4; ++di){
    #pragma unroll
    for (int j = 0; j < 4; ++j){
      int s = q0 + grp * 4 + j;
      float v = acco[di][j] / lrun[j];
      attn_out[((size_t)b * Slen + s) * (NH * HD) + h * HD + di * 16 + lane16] = (bf16_t)v;
    }
  }
}

// ---------------- Output GEMM: attn (8192x576 bf16) @ Wo^T -> fp32 ----------------
__launch_bounds__(256)
__global__ void out_gemm_kernel(const bf16_t* __restrict__ A,
                                const float* __restrict__ Wo,
                                float* __restrict__ out)
{
  __shared__ bf16_t Ald[128 * 72];
  __shared__ bf16_t Bld[64 * 72];
  const int t = threadIdx.x;
  const int l = t & 63;
  const int wid = t >> 6;
  const int wm = wid >> 1, wn = wid & 1;
  const int lane16 = l & 15, grp = l >> 4;
  const int m0 = blockIdx.x * 128;
  const int nt = blockIdx.y;

  const f32x4 fzero = {0.f, 0.f, 0.f, 0.f};
  f32x4 acc[4][2];
  #pragma unroll
  for (int mi = 0; mi < 4; ++mi)
    #pragma unroll
    for (int ni = 0; ni < 2; ++ni)
      acc[mi][ni] = fzero;

  const int rA = t >> 1, kA = (t & 1) * 32;
  const int rB = t >> 2, kB = (t & 3) * 16;

  for (int kt = 0; kt < 9; ++kt){
    {
      const bf16_t* asrc = A + (size_t)(m0 + rA) * Hdim + kt * 64 + kA;
      bf16_t* adst = Ald + rA * 72 + kA;
      #pragma unroll
      for (int u = 0; u < 4; ++u)
        *reinterpret_cast<bf16x8*>(adst + u * 8) = *reinterpret_cast<const bf16x8*>(asrc + u * 8);
      const float* bsrc = Wo + (size_t)(nt * 64 + rB) * Hdim + kt * 64 + kB;
      bf16_t* bdst = Bld + rB * 72 + kB;
      #pragma unroll
      for (int u = 0; u < 2; ++u)
        *reinterpret_cast<bf16x8*>(bdst + u * 8) = load_cvt8(bsrc + u * 8);
    }
    __syncthreads();
    #pragma unroll
    for (int ks = 0; ks < 2; ++ks){
      bf16x8 a[4], bb[2];
      #pragma unroll
      for (int mi = 0; mi < 4; ++mi)
        a[mi] = *reinterpret_cast<const bf16x8*>(&Ald[(wm * 64 + mi * 16 + lane16) * 72 + ks * 32 + grp * 8]);
      #pragma unroll
      for (int ni = 0; ni < 2; ++ni)
        bb[ni] = *reinterpret_cast<const bf16x8*>(&Bld[(wn * 32 + ni * 16 + lane16) * 72 + ks * 32 + grp * 8]);
      #pragma unroll
      for (int mi = 0; mi < 4; ++mi)
        #pragma unroll
        for (int ni = 0; ni < 2; ++ni)
          acc[mi][ni] = __builtin_amdgcn_mfma_f32_16x16x32_bf16(a[mi], bb[ni], acc[mi][ni], 0, 0, 0);
    }
    __syncthreads();
  }

  #pragma unroll
  for (int mi = 0; mi < 4; ++mi){
    #pragma unroll
    for (int ni = 0; ni < 2; ++ni){
      #pragma unroll
      for (int j = 0; j < 4; ++j){
        int m = m0 + wm * 64 + mi * 16 + grp * 4 + j;
        int n = nt * 64 + wn * 32 + ni * 16 + lane16;
        out[(size_t)m * Hdim + n] = acc[mi][ni][j];
      }
    }
  }
}

extern "C" void kernel_launch(void* const* d_in, const int* in_sizes, int n_in,
                              void* d_out, int out_size, void* d_ws, size_t ws_size,
                              hipStream_t stream) {
  const float* X   = (const float*)d_in[0];
  const int* pos   = (const int*)d_in[2];
  const float* Wq  = (const float*)d_in[3];
  const float* Wk  = (const float*)d_in[4];
  const float* Wv  = (const float*)d_in[5];
  const float* Wo  = (const float*)d_in[6];
  float* out = (float*)d_out;

  char* ws = (char*)d_ws;
  float* cost = (float*)ws;
  float* sint = (float*)(ws + (size_t)MAXPOS * 32 * 4);
  bf16_t* qb = (bf16_t*)(ws + 2 * (size_t)MAXPOS * 32 * 4);
  bf16_t* kb = qb + (size_t)Bsz * NH * Slen * HD;
  bf16_t* vt = kb + (size_t)Bsz * NKV * Slen * HD;
  bf16_t* ab = vt + (size_t)Bsz * NKV * Slen * HD;

  const float QSCALE = 0.125f * 1.44269504088896f;  // attn scale folded into log2-domain

  rope_table_kernel<<<dim3((MAXPOS * 32 + 255) / 256), dim3(256), 0, stream>>>(cost, sint);
  qkv_gemm_kernel<<<dim3(64, 15), dim3(256), 0, stream>>>(X, Wq, Wk, Wv, qb, kb, vt);
  rope_apply_kernel<<<dim3((Bsz * NH * Slen + 255) / 256), dim3(256), 0, stream>>>(qb, pos, cost, sint, NH, QSCALE);
  rope_apply_kernel<<<dim3((Bsz * NKV * Slen + 255) / 256), dim3(256), 0, stream>>>(kb, pos, cost, sint, NKV, 1.0f);
  flash_attn_kernel<<<dim3(32, 36), dim3(256), 0, stream>>>(qb, kb, vt, ab);
  out_gemm_kernel<<<dim3(64, 9), dim3(256), 0, stream>>>(ab, Wo, out);
}

// Round 3
// 152.564 us; speedup vs baseline: 1.5402x; 1.1895x over previous
//
#include <hip/hip_runtime.h>
#include <hip/hip_bf16.h>
#include <math.h>

#define Bsz 4
#define Slen 2048
#define Hdim 576
#define NH 9
#define NKV 3
#define HD 64
#define MAXPOS 8192

typedef __bf16 bf16_t;
typedef __bf16 bf16x8 __attribute__((ext_vector_type(8)));
typedef __bf16 bf16x4 __attribute__((ext_vector_type(4)));
typedef __bf16 bf16x2 __attribute__((ext_vector_type(2)));
typedef float f32x4 __attribute__((ext_vector_type(4)));
typedef unsigned int u32;

static __device__ __forceinline__ bf16x8 load_cvt8(const float* __restrict__ src){
  float4 f0 = *reinterpret_cast<const float4*>(src);
  float4 f1 = *reinterpret_cast<const float4*>(src + 4);
  bf16x8 v;
  v[0]=(bf16_t)f0.x; v[1]=(bf16_t)f0.y; v[2]=(bf16_t)f0.z; v[3]=(bf16_t)f0.w;
  v[4]=(bf16_t)f1.x; v[5]=(bf16_t)f1.y; v[6]=(bf16_t)f1.z; v[7]=(bf16_t)f1.w;
  return v;
}

static __device__ __forceinline__ u32 pack_bf16(float a, float b){
  bf16x2 v; v[0] = (bf16_t)a; v[1] = (bf16_t)b;
  return __builtin_bit_cast(u32, v);
}

// async global->LDS, 16B per lane; LDS dest = wave-uniform base + lane*16
static __device__ __forceinline__ void gload16(const bf16_t* g, bf16_t* l){
  __builtin_amdgcn_global_load_lds((const __attribute__((address_space(1))) void*)g,
                                   (__attribute__((address_space(3))) void*)l, 16, 0, 0);
}

// ---------------- RoPE tables: cos/sin[pos][j], j = 0..31 ----------------
__global__ void rope_table_kernel(float* __restrict__ cost, float* __restrict__ sint){
  int i = blockIdx.x * blockDim.x + threadIdx.x;
  if (i >= MAXPOS * 32) return;
  int j = i & 31;
  int p = i >> 5;
  double invf = pow(100000.0, -(double)j / 32.0);
  double ang = (double)p * invf;
  cost[i] = (float)cos(ang);
  sint[i] = (float)sin(ang);
}

// ---------------- QKV projection GEMM (M=8192, K=576, N=960) ----------------
__launch_bounds__(256)
__global__ void qkv_gemm_kernel(const float* __restrict__ X,
                                const float* __restrict__ Wq,
                                const float* __restrict__ Wk,
                                const float* __restrict__ Wv,
                                bf16_t* __restrict__ qbuf,
                                bf16_t* __restrict__ kbuf,
                                bf16_t* __restrict__ vtbuf)
{
  __shared__ bf16_t Ald[128 * 72];
  __shared__ bf16_t Bld[64 * 72];
  const int t = threadIdx.x;
  const int l = t & 63;
  const int wid = t >> 6;
  const int wm = wid >> 1, wn = wid & 1;
  const int lane16 = l & 15, grp = l >> 4;
  const int m0 = blockIdx.x * 128;
  const int nt = blockIdx.y;

  const float* Wsrc;
  int nrow0;
  if (nt < 9)      { Wsrc = Wq; nrow0 = nt * 64; }
  else if (nt < 12){ Wsrc = Wk; nrow0 = (nt - 9) * 64; }
  else             { Wsrc = Wv; nrow0 = (nt - 12) * 64; }

  const f32x4 fzero = {0.f, 0.f, 0.f, 0.f};
  f32x4 acc[4][2];
  #pragma unroll
  for (int mi = 0; mi < 4; ++mi)
    #pragma unroll
    for (int ni = 0; ni < 2; ++ni)
      acc[mi][ni] = fzero;

  const int rA = t >> 1, kA = (t & 1) * 32;
  const int rB = t >> 2, kB = (t & 3) * 16;

  for (int kt = 0; kt < 9; ++kt){
    {
      const float* asrc = X + (size_t)(m0 + rA) * Hdim + kt * 64 + kA;
      bf16_t* adst = Ald + rA * 72 + kA;
      #pragma unroll
      for (int u = 0; u < 4; ++u)
        *reinterpret_cast<bf16x8*>(adst + u * 8) = load_cvt8(asrc + u * 8);
      const float* bsrc = Wsrc + (size_t)(nrow0 + rB) * Hdim + kt * 64 + kB;
      bf16_t* bdst = Bld + rB * 72 + kB;
      #pragma unroll
      for (int u = 0; u < 2; ++u)
        *reinterpret_cast<bf16x8*>(bdst + u * 8) = load_cvt8(bsrc + u * 8);
    }
    __syncthreads();
    #pragma unroll
    for (int ks = 0; ks < 2; ++ks){
      bf16x8 a[4], bb[2];
      #pragma unroll
      for (int mi = 0; mi < 4; ++mi)
        a[mi] = *reinterpret_cast<const bf16x8*>(&Ald[(wm * 64 + mi * 16 + lane16) * 72 + ks * 32 + grp * 8]);
      #pragma unroll
      for (int ni = 0; ni < 2; ++ni)
        bb[ni] = *reinterpret_cast<const bf16x8*>(&Bld[(wn * 32 + ni * 16 + lane16) * 72 + ks * 32 + grp * 8]);
      #pragma unroll
      for (int mi = 0; mi < 4; ++mi)
        #pragma unroll
        for (int ni = 0; ni < 2; ++ni)
          acc[mi][ni] = __builtin_amdgcn_mfma_f32_16x16x32_bf16(a[mi], bb[ni], acc[mi][ni], 0, 0, 0);
    }
    __syncthreads();
  }

  #pragma unroll
  for (int mi = 0; mi < 4; ++mi){
    #pragma unroll
    for (int ni = 0; ni < 2; ++ni){
      #pragma unroll
      for (int j = 0; j < 4; ++j){
        int m = m0 + wm * 64 + mi * 16 + grp * 4 + j;
        int dl = wn * 32 + ni * 16 + lane16;
        int b = m >> 11;
        int s = m & 2047;
        bf16_t v = (bf16_t)acc[mi][ni][j];
        if (nt < 9)
          qbuf[(((size_t)b * NH + nt) * Slen + s) * HD + dl] = v;
        else if (nt < 12)
          kbuf[(((size_t)b * NKV + (nt - 9)) * Slen + s) * HD + dl] = v;
        else
          vtbuf[(((size_t)b * NKV + (nt - 12)) * HD + dl) * Slen + s] = v;
      }
    }
  }
}

// ---------------- RoPE in-place, with output scale (folds attn scale into Q) ----------------
__global__ void rope_apply_kernel(bf16_t* __restrict__ buf, const int* __restrict__ pos_ids,
                                  const float* __restrict__ cost, const float* __restrict__ sint,
                                  int nheads, float scale)
{
  int idx = blockIdx.x * blockDim.x + threadIdx.x;
  int total = Bsz * nheads * Slen;
  if (idx >= total) return;
  int s = idx % Slen;
  int b = idx / (nheads * Slen);
  bf16_t* row = buf + (size_t)idx * HD;
  int pos = pos_ids[b * Slen + s];
  const float* cp = cost + (size_t)pos * 32;
  const float* sp = sint + (size_t)pos * 32;
  float x[64];
  #pragma unroll
  for (int v = 0; v < 8; ++v){
    bf16x8 t8 = *reinterpret_cast<const bf16x8*>(row + v * 8);
    #pragma unroll
    for (int i = 0; i < 8; ++i) x[v * 8 + i] = (float)t8[i];
  }
  bf16_t o[64];
  #pragma unroll
  for (int j = 0; j < 32; ++j){
    float c = cp[j], sn = sp[j];
    o[j]      = (bf16_t)((x[j] * c - x[j + 32] * sn) * scale);
    o[j + 32] = (bf16_t)((x[j + 32] * c + x[j] * sn) * scale);
  }
  #pragma unroll
  for (int v = 0; v < 8; ++v)
    *reinterpret_cast<bf16x8*>(row + v * 8) = *reinterpret_cast<bf16x8*>(o + v * 8);
}

// ---------------- Flash attention v3: swapped-operand QK^T, lane-local softmax ----------------
// Block = 64 q-rows, 4 waves x 16 rows. KV tiles of 64, double-buffered, gload_lds + XOR swizzle.
// QK^T computed as mfma(K,Q) -> P^T (col=q=lane16); softmax in-lane; PV as mfma(V^T,P) -> O^T.
__launch_bounds__(256)
__global__ void flash_attn_kernel(const bf16_t* __restrict__ qbuf,
                                  const bf16_t* __restrict__ kbuf,
                                  const bf16_t* __restrict__ vtbuf,
                                  bf16_t* __restrict__ attn_out)
{
  __shared__ bf16_t Kld[2][64 * 64];
  __shared__ bf16_t Vld[2][64 * 64];
  __shared__ u32 Pld[4][16 * 36];       // per-wave P [16 q][32 words], stride 36 (2-way banks, 16B-aligned rows)
  const int t = threadIdx.x, l = t & 63, w = t >> 6;
  const int lane16 = l & 15, grp = l >> 4;

  // balanced + XCD-chunked schedule: 1152 blocks = 8 XCD chunks of 144
  const int flat = blockIdx.y * 32 + blockIdx.x;
  const int nf = (flat & 7) * 144 + (flat >> 3);
  const int bh = nf >> 5;
  const int qt = 31 - (nf & 31);
  const int b = bh / NH, h = bh % NH, kvh = h / (NH / NKV);

  const bf16_t* qp = qbuf + ((size_t)b * NH + h) * Slen * HD;
  const bf16_t* kp = kbuf + ((size_t)b * NKV + kvh) * Slen * HD;
  const bf16_t* vp = vtbuf + ((size_t)b * NKV + kvh) * HD * Slen;

  const int q0 = qt * 64 + w * 16;
  // Q fragment (B-operand of swapped QK): lane holds Q[q0+lane16][ks*32+grp*8..]
  bf16x8 aq[2];
  #pragma unroll
  for (int ks = 0; ks < 2; ++ks)
    aq[ks] = *reinterpret_cast<const bf16x8*>(qp + (size_t)(q0 + lane16) * HD + ks * 32 + grp * 8);

  const f32x4 fzero = {0.f, 0.f, 0.f, 0.f};
  f32x4 acco[4];                        // O^T: d = di*16+grp*4+j, q = lane16
  #pragma unroll
  for (int di = 0; di < 4; ++di) acco[di] = fzero;
  float mrun = -1e30f, lrun = 0.f;      // scalar per lane (one q-row per lane)

  const int sr = l >> 3;
  const int sc = ((l & 7) ^ sr) * 8;

  const int ntiles = qt + 1;
  int cur = 0;

  {
    #pragma unroll
    for (int u = 0; u < 2; ++u){
      int r = (w * 2 + u) * 8 + sr;
      gload16(kp + (size_t)r * HD + sc, &Kld[0][(w * 2 + u) * 512]);
      gload16(vp + (size_t)r * Slen + sc, &Vld[0][(w * 2 + u) * 512]);
    }
  }
  asm volatile("s_waitcnt vmcnt(0)" ::: "memory");
  __syncthreads();

  for (int kb = 0; kb < ntiles; ++kb){
    if (kb + 1 < ntiles){
      const int k0_ = (kb + 1) * 64;
      #pragma unroll
      for (int u = 0; u < 2; ++u){
        int r = (w * 2 + u) * 8 + sr;
        gload16(kp + (size_t)(k0_ + r) * HD + sc, &Kld[cur ^ 1][(w * 2 + u) * 512]);
        gload16(vp + (size_t)r * Slen + k0_ + sc, &Vld[cur ^ 1][(w * 2 + u) * 512]);
      }
    }

    // ---- QK^T swapped: sacc[ni][j] = S^T[k = ni*16+grp*4+j][q = lane16] ----
    f32x4 sacc[4];
    #pragma unroll
    for (int ni = 0; ni < 4; ++ni) sacc[ni] = fzero;
    #pragma unroll
    for (int ks = 0; ks < 2; ++ks){
      #pragma unroll
      for (int ni = 0; ni < 4; ++ni){
        int row = ni * 16 + lane16;
        bf16x8 bk = *reinterpret_cast<const bf16x8*>(
            &Kld[cur][row * 64 + (((ks * 4 + grp) ^ (row & 7)) * 8)]);
        sacc[ni] = __builtin_amdgcn_mfma_f32_16x16x32_bf16(bk, aq[ks], sacc[ni], 0, 0, 0);
      }
    }

    // ---- causal mask (wave-uniform branch) ----
    if (kb == qt){
      const int wq = w * 16 + lane16;   // within-tile q index
      #pragma unroll
      for (int ni = 0; ni < 4; ++ni)
        #pragma unroll
        for (int j = 0; j < 4; ++j)
          if (ni * 16 + grp * 4 + j > wq) sacc[ni][j] = -1e30f;
    }

    // ---- in-lane row max (tree) + 2 cross-lane rounds ----
    float m01, m23, tmax;
    {
      float a0 = fmaxf(fmaxf(sacc[0][0], sacc[0][1]), fmaxf(sacc[0][2], sacc[0][3]));
      float a1 = fmaxf(fmaxf(sacc[1][0], sacc[1][1]), fmaxf(sacc[1][2], sacc[1][3]));
      float a2 = fmaxf(fmaxf(sacc[2][0], sacc[2][1]), fmaxf(sacc[2][2], sacc[2][3]));
      float a3 = fmaxf(fmaxf(sacc[3][0], sacc[3][1]), fmaxf(sacc[3][2], sacc[3][3]));
      m01 = fmaxf(a0, a1); m23 = fmaxf(a2, a3);
      tmax = fmaxf(m01, m23);
    }
    tmax = fmaxf(tmax, __shfl_xor(tmax, 16, 64));
    tmax = fmaxf(tmax, __shfl_xor(tmax, 32, 64));

    const float mnew = fmaxf(mrun, tmax);
    const float sf = __builtin_amdgcn_exp2f(mrun - mnew);
    mrun = mnew;

    // ---- exp2 + in-lane sum ----
    float rsum = 0.f;
    #pragma unroll
    for (int ni = 0; ni < 4; ++ni){
      #pragma unroll
      for (int j = 0; j < 4; ++j){
        float p = __builtin_amdgcn_exp2f(sacc[ni][j] - mnew);
        sacc[ni][j] = p;
        rsum += p;
      }
    }
    rsum += __shfl_xor(rsum, 16, 64);
    rsum += __shfl_xor(rsum, 32, 64);
    lrun = lrun * sf + rsum;

    #pragma unroll
    for (int di = 0; di < 4; ++di)
      #pragma unroll
      for (int j = 0; j < 4; ++j)
        acco[di][j] *= sf;

    // ---- P pack -> per-wave LDS (word layout = PV B-fragment) ----
    #pragma unroll
    for (int ni = 0; ni < 4; ++ni){
      #pragma unroll
      for (int jp = 0; jp < 2; ++jp)
        Pld[w][lane16 * 36 + ni * 8 + grp * 2 + jp] =
            pack_bf16(sacc[ni][2 * jp], sacc[ni][2 * jp + 1]);
    }

    // ---- PV swapped: mfma(A=V^T, B=P) -> O^T ----
    #pragma unroll
    for (int ks = 0; ks < 2; ++ks){
      bf16x8 pa = *reinterpret_cast<const bf16x8*>(&Pld[w][lane16 * 36 + ks * 16 + grp * 4]);
      #pragma unroll
      for (int di = 0; di < 4; ++di){
        int row = di * 16 + lane16;
        bf16x8 av = *reinterpret_cast<const bf16x8*>(
            &Vld[cur][row * 64 + (((ks * 4 + grp) ^ (row & 7)) * 8)]);
        acco[di] = __builtin_amdgcn_mfma_f32_16x16x32_bf16(av, pa, acco[di], 0, 0, 0);
      }
    }

    asm volatile("s_waitcnt vmcnt(0)" ::: "memory");
    __syncthreads();
    cur ^= 1;
  }

  // ---- epilogue: one rcp per lane, 8B stores ----
  const float linv = 1.0f / lrun;
  const int s = q0 + lane16;
  #pragma unroll
  for (int di = 0; di < 4; ++di){
    bf16x4 o4;
    #pragma unroll
    for (int j = 0; j < 4; ++j) o4[j] = (bf16_t)(acco[di][j] * linv);
    *reinterpret_cast<bf16x4*>(
        attn_out + ((size_t)b * Slen + s) * (NH * HD) + h * HD + di * 16 + grp * 4) = o4;
  }
}

// ---------------- Output GEMM: attn (8192x576 bf16) @ Wo^T -> fp32 ----------------
__launch_bounds__(256)
__global__ void out_gemm_kernel(const bf16_t* __restrict__ A,
                                const float* __restrict__ Wo,
                                float* __restrict__ out)
{
  __shared__ bf16_t Ald[128 * 72];
  __shared__ bf16_t Bld[64 * 72];
  const int t = threadIdx.x;
  const int l = t & 63;
  const int wid = t >> 6;
  const int wm = wid >> 1, wn = wid & 1;
  const int lane16 = l & 15, grp = l >> 4;
  const int m0 = blockIdx.x * 128;
  const int nt = blockIdx.y;

  const f32x4 fzero = {0.f, 0.f, 0.f, 0.f};
  f32x4 acc[4][2];
  #pragma unroll
  for (int mi = 0; mi < 4; ++mi)
    #pragma unroll
    for (int ni = 0; ni < 2; ++ni)
      acc[mi][ni] = fzero;

  const int rA = t >> 1, kA = (t & 1) * 32;
  const int rB = t >> 2, kB = (t & 3) * 16;

  for (int kt = 0; kt < 9; ++kt){
    {
      const bf16_t* asrc = A + (size_t)(m0 + rA) * Hdim + kt * 64 + kA;
      bf16_t* adst = Ald + rA * 72 + kA;
      #pragma unroll
      for (int u = 0; u < 4; ++u)
        *reinterpret_cast<bf16x8*>(adst + u * 8) = *reinterpret_cast<const bf16x8*>(asrc + u * 8);
      const float* bsrc = Wo + (size_t)(nt * 64 + rB) * Hdim + kt * 64 + kB;
      bf16_t* bdst = Bld + rB * 72 + kB;
      #pragma unroll
      for (int u = 0; u < 2; ++u)
        *reinterpret_cast<bf16x8*>(bdst + u * 8) = load_cvt8(bsrc + u * 8);
    }
    __syncthreads();
    #pragma unroll
    for (int ks = 0; ks < 2; ++ks){
      bf16x8 a[4], bb[2];
      #pragma unroll
      for (int mi = 0; mi < 4; ++mi)
        a[mi] = *reinterpret_cast<const bf16x8*>(&Ald[(wm * 64 + mi * 16 + lane16) * 72 + ks * 32 + grp * 8]);
      #pragma unroll
      for (int ni = 0; ni < 2; ++ni)
        bb[ni] = *reinterpret_cast<const bf16x8*>(&Bld[(wn * 32 + ni * 16 + lane16) * 72 + ks * 32 + grp * 8]);
      #pragma unroll
      for (int mi = 0; mi < 4; ++mi)
        #pragma unroll
        for (int ni = 0; ni < 2; ++ni)
          acc[mi][ni] = __builtin_amdgcn_mfma_f32_16x16x32_bf16(a[mi], bb[ni], acc[mi][ni], 0, 0, 0);
    }
    __syncthreads();
  }

  #pragma unroll
  for (int mi = 0; mi < 4; ++mi){
    #pragma unroll
    for (int ni = 0; ni < 2; ++ni){
      #pragma unroll
      for (int j = 0; j < 4; ++j){
        int m = m0 + wm * 64 + mi * 16 + grp * 4 + j;
        int n = nt * 64 + wn * 32 + ni * 16 + lane16;
        out[(size_t)m * Hdim + n] = acc[mi][ni][j];
      }
    }
  }
}

extern "C" void kernel_launch(void* const* d_in, const int* in_sizes, int n_in,
                              void* d_out, int out_size, void* d_ws, size_t ws_size,
                              hipStream_t stream) {
  const float* X   = (const float*)d_in[0];
  const int* pos   = (const int*)d_in[2];
  const float* Wq  = (const float*)d_in[3];
  const float* Wk  = (const float*)d_in[4];
  const float* Wv  = (const float*)d_in[5];
  const float* Wo  = (const float*)d_in[6];
  float* out = (float*)d_out;

  char* ws = (char*)d_ws;
  float* cost = (float*)ws;
  float* sint = (float*)(ws + (size_t)MAXPOS * 32 * 4);
  bf16_t* qb = (bf16_t*)(ws + 2 * (size_t)MAXPOS * 32 * 4);
  bf16_t* kb = qb + (size_t)Bsz * NH * Slen * HD;
  bf16_t* vt = kb + (size_t)Bsz * NKV * Slen * HD;
  bf16_t* ab = vt + (size_t)Bsz * NKV * Slen * HD;

  const float QSCALE = 0.125f * 1.44269504088896f;

  rope_table_kernel<<<dim3((MAXPOS * 32 + 255) / 256), dim3(256), 0, stream>>>(cost, sint);
  qkv_gemm_kernel<<<dim3(64, 15), dim3(256), 0, stream>>>(X, Wq, Wk, Wv, qb, kb, vt);
  rope_apply_kernel<<<dim3((Bsz * NH * Slen + 255) / 256), dim3(256), 0, stream>>>(qb, pos, cost, sint, NH, QSCALE);
  rope_apply_kernel<<<dim3((Bsz * NKV * Slen + 255) / 256), dim3(256), 0, stream>>>(kb, pos, cost, sint, NKV, 1.0f);
  flash_attn_kernel<<<dim3(32, 36), dim3(256), 0, stream>>>(qb, kb, vt, ab);
  out_gemm_kernel<<<dim3(64, 9), dim3(256), 0, stream>>>(ab, Wo, out);
}

// Round 4
// 145.047 us; speedup vs baseline: 1.6200x; 1.0518x over previous
//
#include <hip/hip_runtime.h>
#include <hip/hip_bf16.h>
#include <math.h>

#define Bsz 4
#define Slen 2048
#define Hdim 576
#define NH 9
#define NKV 3
#define HD 64
#define MAXPOS 8192

typedef __bf16 bf16_t;
typedef __bf16 bf16x8 __attribute__((ext_vector_type(8)));
typedef __bf16 bf16x4 __attribute__((ext_vector_type(4)));
typedef __bf16 bf16x2 __attribute__((ext_vector_type(2)));
typedef float f32x4 __attribute__((ext_vector_type(4)));
typedef float f32x16 __attribute__((ext_vector_type(16)));
typedef unsigned int u32;
typedef unsigned int u32x4 __attribute__((ext_vector_type(4)));

static __device__ __forceinline__ bf16x8 load_cvt8(const float* __restrict__ src){
  float4 f0 = *reinterpret_cast<const float4*>(src);
  float4 f1 = *reinterpret_cast<const float4*>(src + 4);
  bf16x8 v;
  v[0]=(bf16_t)f0.x; v[1]=(bf16_t)f0.y; v[2]=(bf16_t)f0.z; v[3]=(bf16_t)f0.w;
  v[4]=(bf16_t)f1.x; v[5]=(bf16_t)f1.y; v[6]=(bf16_t)f1.z; v[7]=(bf16_t)f1.w;
  return v;
}

// async global->LDS, 16B per lane
static __device__ __forceinline__ void gload16(const bf16_t* g, bf16_t* l){
  __builtin_amdgcn_global_load_lds((const __attribute__((address_space(1))) void*)g,
                                   (__attribute__((address_space(3))) void*)l, 16, 0, 0);
}

// ---------------- RoPE tables ----------------
__global__ void rope_table_kernel(float* __restrict__ cost, float* __restrict__ sint){
  int i = blockIdx.x * blockDim.x + threadIdx.x;
  if (i >= MAXPOS * 32) return;
  int j = i & 31;
  int p = i >> 5;
  double invf = pow(100000.0, -(double)j / 32.0);
  double ang = (double)p * invf;
  cost[i] = (float)cos(ang);
  sint[i] = (float)sin(ang);
}

// ---------------- QKV projection GEMM (M=8192, K=576, N=960) ----------------
__launch_bounds__(256)
__global__ void qkv_gemm_kernel(const float* __restrict__ X,
                                const float* __restrict__ Wq,
                                const float* __restrict__ Wk,
                                const float* __restrict__ Wv,
                                bf16_t* __restrict__ qbuf,
                                bf16_t* __restrict__ kbuf,
                                bf16_t* __restrict__ vtbuf)
{
  __shared__ bf16_t Ald[128 * 72];
  __shared__ bf16_t Bld[64 * 72];
  const int t = threadIdx.x;
  const int l = t & 63;
  const int wid = t >> 6;
  const int wm = wid >> 1, wn = wid & 1;
  const int lane16 = l & 15, grp = l >> 4;
  const int m0 = blockIdx.x * 128;
  const int nt = blockIdx.y;

  const float* Wsrc;
  int nrow0;
  if (nt < 9)      { Wsrc = Wq; nrow0 = nt * 64; }
  else if (nt < 12){ Wsrc = Wk; nrow0 = (nt - 9) * 64; }
  else             { Wsrc = Wv; nrow0 = (nt - 12) * 64; }

  const f32x4 fzero = {0.f, 0.f, 0.f, 0.f};
  f32x4 acc[4][2];
  #pragma unroll
  for (int mi = 0; mi < 4; ++mi)
    #pragma unroll
    for (int ni = 0; ni < 2; ++ni)
      acc[mi][ni] = fzero;

  const int rA = t >> 1, kA = (t & 1) * 32;
  const int rB = t >> 2, kB = (t & 3) * 16;

  for (int kt = 0; kt < 9; ++kt){
    {
      const float* asrc = X + (size_t)(m0 + rA) * Hdim + kt * 64 + kA;
      bf16_t* adst = Ald + rA * 72 + kA;
      #pragma unroll
      for (int u = 0; u < 4; ++u)
        *reinterpret_cast<bf16x8*>(adst + u * 8) = load_cvt8(asrc + u * 8);
      const float* bsrc = Wsrc + (size_t)(nrow0 + rB) * Hdim + kt * 64 + kB;
      bf16_t* bdst = Bld + rB * 72 + kB;
      #pragma unroll
      for (int u = 0; u < 2; ++u)
        *reinterpret_cast<bf16x8*>(bdst + u * 8) = load_cvt8(bsrc + u * 8);
    }
    __syncthreads();
    #pragma unroll
    for (int ks = 0; ks < 2; ++ks){
      bf16x8 a[4], bb[2];
      #pragma unroll
      for (int mi = 0; mi < 4; ++mi)
        a[mi] = *reinterpret_cast<const bf16x8*>(&Ald[(wm * 64 + mi * 16 + lane16) * 72 + ks * 32 + grp * 8]);
      #pragma unroll
      for (int ni = 0; ni < 2; ++ni)
        bb[ni] = *reinterpret_cast<const bf16x8*>(&Bld[(wn * 32 + ni * 16 + lane16) * 72 + ks * 32 + grp * 8]);
      #pragma unroll
      for (int mi = 0; mi < 4; ++mi)
        #pragma unroll
        for (int ni = 0; ni < 2; ++ni)
          acc[mi][ni] = __builtin_amdgcn_mfma_f32_16x16x32_bf16(a[mi], bb[ni], acc[mi][ni], 0, 0, 0);
    }
    __syncthreads();
  }

  #pragma unroll
  for (int mi = 0; mi < 4; ++mi){
    #pragma unroll
    for (int ni = 0; ni < 2; ++ni){
      #pragma unroll
      for (int j = 0; j < 4; ++j){
        int m = m0 + wm * 64 + mi * 16 + grp * 4 + j;
        int dl = wn * 32 + ni * 16 + lane16;
        int b = m >> 11;
        int s = m & 2047;
        bf16_t v = (bf16_t)acc[mi][ni][j];
        if (nt < 9)
          qbuf[(((size_t)b * NH + nt) * Slen + s) * HD + dl] = v;
        else if (nt < 12)
          kbuf[(((size_t)b * NKV + (nt - 9)) * Slen + s) * HD + dl] = v;
        else
          vtbuf[(((size_t)b * NKV + (nt - 12)) * HD + dl) * Slen + s] = v;
      }
    }
  }
}

// ---------------- RoPE in-place ----------------
__global__ void rope_apply_kernel(bf16_t* __restrict__ buf, const int* __restrict__ pos_ids,
                                  const float* __restrict__ cost, const float* __restrict__ sint,
                                  int nheads, float scale)
{
  int idx = blockIdx.x * blockDim.x + threadIdx.x;
  int total = Bsz * nheads * Slen;
  if (idx >= total) return;
  int s = idx % Slen;
  int b = idx / (nheads * Slen);
  bf16_t* row = buf + (size_t)idx * HD;
  int pos = pos_ids[b * Slen + s];
  const float* cp = cost + (size_t)pos * 32;
  const float* sp = sint + (size_t)pos * 32;
  float x[64];
  #pragma unroll
  for (int v = 0; v < 8; ++v){
    bf16x8 t8 = *reinterpret_cast<const bf16x8*>(row + v * 8);
    #pragma unroll
    for (int i = 0; i < 8; ++i) x[v * 8 + i] = (float)t8[i];
  }
  bf16_t o[64];
  #pragma unroll
  for (int j = 0; j < 32; ++j){
    float c = cp[j], sn = sp[j];
    o[j]      = (bf16_t)((x[j] * c - x[j + 32] * sn) * scale);
    o[j + 32] = (bf16_t)((x[j + 32] * c + x[j] * sn) * scale);
  }
  #pragma unroll
  for (int v = 0; v < 8; ++v)
    *reinterpret_cast<bf16x8*>(row + v * 8) = *reinterpret_cast<bf16x8*>(o + v * 8);
}

// ---------------- Flash attention v4: 32x32 swapped MFMA, reg-only P, balanced grid ----------------
// Block = 64 q-rows, 2 waves x 32 q. KV tiles of 64, dbuf, gload_lds + XOR swizzle. No LDS for P.
__launch_bounds__(128)
__global__ void flash_attn_kernel(const bf16_t* __restrict__ qbuf,
                                  const bf16_t* __restrict__ kbuf,
                                  const bf16_t* __restrict__ vtbuf,
                                  bf16_t* __restrict__ attn_out)
{
  __shared__ bf16_t Kld[2][64 * 64];
  __shared__ bf16_t Vld[2][64 * 64];
  const int t = threadIdx.x, l = t & 63, w = t >> 6;     // w in 0..1
  const int l32 = l & 31, hi = l >> 5;

  // balanced schedule: same-CU (stride-256) blocks get alternating big/small qt
  const int flat = blockIdx.x;
  const int iq = flat / 36;
  const int bh = flat % 36;
  const int qt = (iq & 1) ? (iq >> 1) : (31 - (iq >> 1));
  const int b = bh / NH, h = bh % NH, kvh = h / (NH / NKV);

  const bf16_t* qp = qbuf + ((size_t)b * NH + h) * Slen * HD;
  const bf16_t* kp = kbuf + ((size_t)b * NKV + kvh) * Slen * HD;
  const bf16_t* vp = vtbuf + ((size_t)b * NKV + kvh) * HD * Slen;

  const int q0 = qt * 64 + w * 32;
  // Q = B-operand of swapped QK (32x32x16): lane holds Q[q0+l32][ds*16 + hi*8 + i]
  bf16x8 aq[4];
  #pragma unroll
  for (int ds = 0; ds < 4; ++ds)
    aq[ds] = *reinterpret_cast<const bf16x8*>(qp + (size_t)(q0 + l32) * HD + ds * 16 + hi * 8);

  f32x16 acco[2];   // O^T[d = db*32 + crow(r,hi)][q = l32]
  #pragma unroll
  for (int db = 0; db < 2; ++db)
    #pragma unroll
    for (int r = 0; r < 16; ++r) acco[db][r] = 0.f;
  float mrun = -1e30f, lrun = 0.f;

  const int sr = l >> 3;
  const int sc = ((l & 7) ^ sr) * 8;

  const int ntiles = qt + 1;
  int cur = 0;

  { // prologue: stage tile 0
    #pragma unroll
    for (int u = 0; u < 4; ++u){
      int r = (w * 4 + u) * 8 + sr;
      gload16(kp + (size_t)r * HD + sc, &Kld[0][(w * 4 + u) * 512]);
      gload16(vp + (size_t)r * Slen + sc, &Vld[0][(w * 4 + u) * 512]);
    }
  }
  asm volatile("s_waitcnt vmcnt(0)" ::: "memory");
  __syncthreads();

  for (int kb = 0; kb < ntiles; ++kb){
    if (kb + 1 < ntiles){
      const int k0_ = (kb + 1) * 64;
      #pragma unroll
      for (int u = 0; u < 4; ++u){
        int r = (w * 4 + u) * 8 + sr;
        gload16(kp + (size_t)(k0_ + r) * HD + sc, &Kld[cur ^ 1][(w * 4 + u) * 512]);
        gload16(vp + (size_t)r * Slen + k0_ + sc, &Vld[cur ^ 1][(w * 4 + u) * 512]);
      }
    }

    // ---- QK^T swapped: sacc[kb2] = S^T[k = kb2*32 + crow(r,hi)][q = l32] ----
    f32x16 sacc[2];
    #pragma unroll
    for (int kb2 = 0; kb2 < 2; ++kb2)
      #pragma unroll
      for (int r = 0; r < 16; ++r) sacc[kb2][r] = 0.f;

    __builtin_amdgcn_s_setprio(1);
    #pragma unroll
    for (int ds = 0; ds < 4; ++ds){
      #pragma unroll
      for (int kb2 = 0; kb2 < 2; ++kb2){
        int row = kb2 * 32 + l32;
        bf16x8 ak = *reinterpret_cast<const bf16x8*>(
            &Kld[cur][row * 64 + (((ds * 2 + hi) ^ (row & 7)) * 8)]);
        sacc[kb2] = __builtin_amdgcn_mfma_f32_32x32x16_bf16(ak, aq[ds], sacc[kb2], 0, 0, 0);
      }
    }
    __builtin_amdgcn_s_setprio(0);

    // ---- causal mask (diag tile only); crow(r,hi) = (r&3) + 8*(r>>2) + 4*hi ----
    if (kb == qt){
      const int q_wt = w * 32 + l32;
      #pragma unroll
      for (int kb2 = 0; kb2 < 2; ++kb2)
        #pragma unroll
        for (int r = 0; r < 16; ++r){
          int k_wt = kb2 * 32 + (r & 3) + 8 * (r >> 2) + 4 * hi;
          if (k_wt > q_wt) sacc[kb2][r] = -1e30f;
        }
    }

    // ---- row max: in-lane tree + 1 cross (lane pair l, l^32 shares q) ----
    float tmax;
    {
      float m0_ = fmaxf(sacc[0][0], sacc[0][1]);
      #pragma unroll
      for (int r = 2; r < 16; ++r) m0_ = fmaxf(m0_, sacc[0][r]);
      float m1_ = fmaxf(sacc[1][0], sacc[1][1]);
      #pragma unroll
      for (int r = 2; r < 16; ++r) m1_ = fmaxf(m1_, sacc[1][r]);
      tmax = fmaxf(m0_, m1_);
    }
    tmax = fmaxf(tmax, __shfl_xor(tmax, 32, 64));

    // ---- defer-max (THR = 8 in log2 domain) ----
    if (__ballot(tmax - mrun > 8.f)){
      float mnew = fmaxf(mrun, tmax);
      float sf = __builtin_amdgcn_exp2f(mrun - mnew);
      lrun *= sf;
      #pragma unroll
      for (int db = 0; db < 2; ++db)
        #pragma unroll
        for (int r = 0; r < 16; ++r) acco[db][r] *= sf;
      mrun = mnew;
    }

    // ---- exp2 + row sum ----
    float rs0 = 0.f, rs1 = 0.f;
    #pragma unroll
    for (int kb2 = 0; kb2 < 2; ++kb2){
      #pragma unroll
      for (int r = 0; r < 16; ++r){
        float p = __builtin_amdgcn_exp2f(sacc[kb2][r] - mrun);
        sacc[kb2][r] = p;
        if (kb2) rs1 += p; else rs0 += p;
      }
    }
    float rsum = rs0 + rs1;
    rsum += __shfl_xor(rsum, 32, 64);
    lrun += rsum;

    // ---- P -> bf16 PV fragments, in-register (cvt_pk + permlane32_swap) ----
    u32x4 pa[4];    // pa[ks]: B-frag P^T[k = ks*16 + hi*8 + i][q = l32]
    #pragma unroll
    for (int kb2 = 0; kb2 < 2; ++kb2){
      u32 wv[8];
      #pragma unroll
      for (int j = 0; j < 8; ++j){
        float lo = sacc[kb2][2 * j], hp = sacc[kb2][2 * j + 1];
        asm("v_cvt_pk_bf16_f32 %0, %1, %2" : "=v"(wv[j]) : "v"(lo), "v"(hp));
      }
      asm volatile("v_permlane32_swap_b32 %0, %1" : "+v"(wv[0]), "+v"(wv[2]));
      asm volatile("v_permlane32_swap_b32 %0, %1" : "+v"(wv[1]), "+v"(wv[3]));
      asm volatile("v_permlane32_swap_b32 %0, %1" : "+v"(wv[4]), "+v"(wv[6]));
      asm volatile("v_permlane32_swap_b32 %0, %1" : "+v"(wv[5]), "+v"(wv[7]));
      pa[2 * kb2]     = (u32x4){wv[0], wv[1], wv[2], wv[3]};
      pa[2 * kb2 + 1] = (u32x4){wv[4], wv[5], wv[6], wv[7]};
    }

    // ---- PV swapped: acco[db] += mfma(A = V^T, B = P^T) ----
    __builtin_amdgcn_s_setprio(1);
    #pragma unroll
    for (int ks = 0; ks < 4; ++ks){
      #pragma unroll
      for (int db = 0; db < 2; ++db){
        int row = db * 32 + l32;
        bf16x8 av = *reinterpret_cast<const bf16x8*>(
            &Vld[cur][row * 64 + (((ks * 2 + hi) ^ (row & 7)) * 8)]);
        acco[db] = __builtin_amdgcn_mfma_f32_32x32x16_bf16(
            av, __builtin_bit_cast(bf16x8, pa[ks]), acco[db], 0, 0, 0);
      }
    }
    __builtin_amdgcn_s_setprio(0);

    asm volatile("s_waitcnt vmcnt(0)" ::: "memory");
    __syncthreads();
    cur ^= 1;
  }

  // ---- epilogue: O[q][d] = acco^T / lrun; pack d-pairs -> 4B stores ----
  const float linv = 1.0f / lrun;
  const int srow = q0 + l32;
  bf16_t* orow = attn_out + ((size_t)b * Slen + srow) * (NH * HD) + h * HD;
  #pragma unroll
  for (int db = 0; db < 2; ++db){
    #pragma unroll
    for (int j = 0; j < 8; ++j){
      int r = 2 * j;
      int d = db * 32 + (r & 3) + 8 * (r >> 2) + 4 * hi;   // even, consecutive pair
      u32 pw;
      float lo = acco[db][r] * linv, hp = acco[db][r + 1] * linv;
      asm("v_cvt_pk_bf16_f32 %0, %1, %2" : "=v"(pw) : "v"(lo), "v"(hp));
      *reinterpret_cast<u32*>(orow + d) = pw;
    }
  }
}

// ---------------- Output GEMM: attn (8192x576 bf16) @ Wo^T -> fp32 ----------------
__launch_bounds__(256)
__global__ void out_gemm_kernel(const bf16_t* __restrict__ A,
                                const float* __restrict__ Wo,
                                float* __restrict__ out)
{
  __shared__ bf16_t Ald[128 * 72];
  __shared__ bf16_t Bld[64 * 72];
  const int t = threadIdx.x;
  const int l = t & 63;
  const int wid = t >> 6;
  const int wm = wid >> 1, wn = wid & 1;
  const int lane16 = l & 15, grp = l >> 4;
  const int m0 = blockIdx.x * 128;
  const int nt = blockIdx.y;

  const f32x4 fzero = {0.f, 0.f, 0.f, 0.f};
  f32x4 acc[4][2];
  #pragma unroll
  for (int mi = 0; mi < 4; ++mi)
    #pragma unroll
    for (int ni = 0; ni < 2; ++ni)
      acc[mi][ni] = fzero;

  const int rA = t >> 1, kA = (t & 1) * 32;
  const int rB = t >> 2, kB = (t & 3) * 16;

  for (int kt = 0; kt < 9; ++kt){
    {
      const bf16_t* asrc = A + (size_t)(m0 + rA) * Hdim + kt * 64 + kA;
      bf16_t* adst = Ald + rA * 72 + kA;
      #pragma unroll
      for (int u = 0; u < 4; ++u)
        *reinterpret_cast<bf16x8*>(adst + u * 8) = *reinterpret_cast<const bf16x8*>(asrc + u * 8);
      const float* bsrc = Wo + (size_t)(nt * 64 + rB) * Hdim + kt * 64 + kB;
      bf16_t* bdst = Bld + rB * 72 + kB;
      #pragma unroll
      for (int u = 0; u < 2; ++u)
        *reinterpret_cast<bf16x8*>(bdst + u * 8) = load_cvt8(bsrc + u * 8);
    }
    __syncthreads();
    #pragma unroll
    for (int ks = 0; ks < 2; ++ks){
      bf16x8 a[4], bb[2];
      #pragma unroll
      for (int mi = 0; mi < 4; ++mi)
        a[mi] = *reinterpret_cast<const bf16x8*>(&Ald[(wm * 64 + mi * 16 + lane16) * 72 + ks * 32 + grp * 8]);
      #pragma unroll
      for (int ni = 0; ni < 2; ++ni)
        bb[ni] = *reinterpret_cast<const bf16x8*>(&Bld[(wn * 32 + ni * 16 + lane16) * 72 + ks * 32 + grp * 8]);
      #pragma unroll
      for (int mi = 0; mi < 4; ++mi)
        #pragma unroll
        for (int ni = 0; ni < 2; ++ni)
          acc[mi][ni] = __builtin_amdgcn_mfma_f32_16x16x32_bf16(a[mi], bb[ni], acc[mi][ni], 0, 0, 0);
    }
    __syncthreads();
  }

  #pragma unroll
  for (int mi = 0; mi < 4; ++mi){
    #pragma unroll
    for (int ni = 0; ni < 2; ++ni){
      #pragma unroll
      for (int j = 0; j < 4; ++j){
        int m = m0 + wm * 64 + mi * 16 + grp * 4 + j;
        int n = nt * 64 + wn * 32 + ni * 16 + lane16;
        out[(size_t)m * Hdim + n] = acc[mi][ni][j];
      }
    }
  }
}

extern "C" void kernel_launch(void* const* d_in, const int* in_sizes, int n_in,
                              void* d_out, int out_size, void* d_ws, size_t ws_size,
                              hipStream_t stream) {
  const float* X   = (const float*)d_in[0];
  const int* pos   = (const int*)d_in[2];
  const float* Wq  = (const float*)d_in[3];
  const float* Wk  = (const float*)d_in[4];
  const float* Wv  = (const float*)d_in[5];
  const float* Wo  = (const float*)d_in[6];
  float* out = (float*)d_out;

  char* ws = (char*)d_ws;
  float* cost = (float*)ws;
  float* sint = (float*)(ws + (size_t)MAXPOS * 32 * 4);
  bf16_t* qb = (bf16_t*)(ws + 2 * (size_t)MAXPOS * 32 * 4);
  bf16_t* kb = qb + (size_t)Bsz * NH * Slen * HD;
  bf16_t* vt = kb + (size_t)Bsz * NKV * Slen * HD;
  bf16_t* ab = vt + (size_t)Bsz * NKV * Slen * HD;

  const float QSCALE = 0.125f * 1.44269504088896f;

  rope_table_kernel<<<dim3((MAXPOS * 32 + 255) / 256), dim3(256), 0, stream>>>(cost, sint);
  qkv_gemm_kernel<<<dim3(64, 15), dim3(256), 0, stream>>>(X, Wq, Wk, Wv, qb, kb, vt);
  rope_apply_kernel<<<dim3((Bsz * NH * Slen + 255) / 256), dim3(256), 0, stream>>>(qb, pos, cost, sint, NH, QSCALE);
  rope_apply_kernel<<<dim3((Bsz * NKV * Slen + 255) / 256), dim3(256), 0, stream>>>(kb, pos, cost, sint, NKV, 1.0f);
  flash_attn_kernel<<<dim3(1152), dim3(128), 0, stream>>>(qb, kb, vt, ab);
  out_gemm_kernel<<<dim3(64, 9), dim3(256), 0, stream>>>(ab, Wo, out);
}